// Round 1
// baseline (667.853 us; speedup 1.0000x reference)
//
#include <hip/hip_runtime.h>

// B=4, S=2048, D=768, H=12, DH=64
// out = [ ctx (B*S*D fp32) | probs (B*H*S*S fp32) ]
#define BB 4
#define SS 2048
#define DD 768
#define HH 12

typedef unsigned short u16t;
typedef unsigned char  u8t;
typedef unsigned int   u32t;
typedef __attribute__((ext_vector_type(8))) short bf16x8;
typedef __attribute__((ext_vector_type(4))) float f32x4;

union FragU { bf16x8 v; ushort4 h[2]; };

__device__ __forceinline__ u16t f2bf(float f) {
  union { float fv; u32t u; } x; x.fv = f;
  u32t r = x.u + 0x7FFFu + ((x.u >> 16) & 1u);   // RNE f32 -> bf16
  return (u16t)(r >> 16);
}

// ---- mask dtype detector: flag = 0 int32(0/1), 1 bool bytes, 2 float32(0/1) ----
__global__ void detect_kernel(const u32t* __restrict__ mp, int* __restrict__ flag)
{
  __shared__ int s_isb, s_isf;
  if (threadIdx.x == 0) { s_isb = 0; s_isf = 0; }
  __syncthreads();
  int isb = 0, isf = 0;
  for (int i = threadIdx.x; i < 16384; i += 256) {   // first 64 KB
    u32t v = mp[i];
    if ((v & 0xFF000000u) == 0x3F000000u) isf = 1;   // a 1.0f word
    else if (v & 0xFFFFFF00u) isb = 1;               // upper bytes populated -> bool
  }
  if (isb) atomicOr(&s_isb, 1);
  if (isf) atomicOr(&s_isf, 1);
  __syncthreads();
  if (threadIdx.x == 0) *flag = s_isf ? 2 : (s_isb ? 1 : 0);
}

// ---- projection: out[m][n] = bf16( X[m][:] @ W[:][n] + bias[n] ) ----
// X [8192][768] fp32, W [768][768] fp32 (row=in, col=out). Tile 64M x 128N, BK=32.
__global__ __launch_bounds__(256)
void proj_kernel(const float* __restrict__ X, const float* __restrict__ W,
                 const float* __restrict__ bias, u16t* __restrict__ out)
{
  __shared__ u16t Al[64 * 40];    // [row][k], padded to 40 shorts
  __shared__ u16t Bl[128 * 40];   // [n][k] (W transposed), padded + xor-swizzled
  const int t = threadIdx.x;
  const int w = t >> 6;
  const int l = t & 63;
  const int lq = l & 15, lg = l >> 4;
  const int m0 = blockIdx.x * 64;
  const int n0 = blockIdx.y * 128;
  const f32x4 fzero = {0.f, 0.f, 0.f, 0.f};

  f32x4 acc[8];
#pragma unroll
  for (int i = 0; i < 8; ++i) acc[i] = fzero;

  const int ar = t >> 2, ac = (t & 3) * 8;  // A staging coords
  const int bn = (t & 15) * 8;              // B staging col base

  for (int kk = 0; kk < DD; kk += 32) {
    { // stage A: 64 rows x 32 k, fp32 -> bf16
      const float* s = X + (size_t)(m0 + ar) * DD + kk + ac;
      float4 f0 = *(const float4*)s;
      float4 f1 = *(const float4*)(s + 4);
      u16t* d = &Al[ar * 40 + ac];
      d[0] = f2bf(f0.x); d[1] = f2bf(f0.y); d[2] = f2bf(f0.z); d[3] = f2bf(f0.w);
      d[4] = f2bf(f1.x); d[5] = f2bf(f1.y); d[6] = f2bf(f1.z); d[7] = f2bf(f1.w);
    }
#pragma unroll
    for (int rep = 0; rep < 2; ++rep) { // stage B transposed: Bl[n][c] = W[kk+c][n0+n]
      const int c = (t >> 4) + rep * 16;
      const float* s = W + (size_t)(kk + c) * DD + n0 + bn;
      float4 f0 = *(const float4*)s;
      float4 f1 = *(const float4*)(s + 4);
      float fv[8] = {f0.x, f0.y, f0.z, f0.w, f1.x, f1.y, f1.z, f1.w};
#pragma unroll
      for (int e = 0; e < 8; ++e) {
        const int n = bn + e;
        Bl[n * 40 + (c ^ (((n >> 3) & 3) * 8))] = f2bf(fv[e]);
      }
    }
    __syncthreads();
    FragU a;
    const int arow = w * 16 + lq;
    a.h[0] = *(const ushort4*)&Al[arow * 40 + 4 * lg];
    a.h[1] = *(const ushort4*)&Al[arow * 40 + 4 * lg + 16];
#pragma unroll
    for (int nt = 0; nt < 8; ++nt) {
      const int bcol = nt * 16 + lq;
      const int xb = ((bcol >> 3) & 3) * 8;
      FragU bfr;
      bfr.h[0] = *(const ushort4*)&Bl[bcol * 40 + ((4 * lg) ^ xb)];
      bfr.h[1] = *(const ushort4*)&Bl[bcol * 40 + ((4 * lg + 16) ^ xb)];
      acc[nt] = __builtin_amdgcn_mfma_f32_16x16x32_bf16(a.v, bfr.v, acc[nt], 0, 0, 0);
    }
    __syncthreads();
  }
#pragma unroll
  for (int nt = 0; nt < 8; ++nt) {
    const int n = n0 + nt * 16 + lq;
    const float bb = bias[n];
#pragma unroll
    for (int r = 0; r < 4; ++r)
      out[(size_t)(m0 + w * 16 + 4 * lg + r) * DD + n] = f2bf(acc[nt][r] + bb);
  }
}

// ---- attention staging helpers ----
// K tile: LDS [kr 0..127][d 0..63] bf16, xor-swizzled: elem(kr,k) at kr*64 + (k ^ ((kr&7)*8))
__device__ __forceinline__ void stage_kv(const u16t* __restrict__ src_row,
                                         u16t* __restrict__ dst, int sr, int sh)
{
  const int kx = (sr & 7) * 8;
#pragma unroll
  for (int i = 0; i < 4; ++i) {
    uint4 val = *(const uint4*)(src_row + sh * 32 + i * 8);
    *(uint4*)&dst[sr * 64 + ((sh * 32 + i * 8) ^ kx)] = val;
  }
}

// V tile transposed: LDS [d 0..63][kr 0..127] bf16: elem(d,kr) at d*128 + (kr ^ ((d&7)*8))
__device__ __forceinline__ void stage_vt(const u16t* __restrict__ src_row,
                                         u16t* __restrict__ Vt, int sr, int sh)
{
#pragma unroll
  for (int i = 0; i < 4; ++i) {
    ushort4 v0 = *(const ushort4*)(src_row + sh * 32 + i * 8);
    ushort4 v1 = *(const ushort4*)(src_row + sh * 32 + i * 8 + 4);
    const int d0 = sh * 32 + i * 8;         // multiple of 8 -> (d0+e)&7 == e
    Vt[(d0 + 0) * 128 + (sr ^  0)] = v0.x;
    Vt[(d0 + 1) * 128 + (sr ^  8)] = v0.y;
    Vt[(d0 + 2) * 128 + (sr ^ 16)] = v0.z;
    Vt[(d0 + 3) * 128 + (sr ^ 24)] = v0.w;
    Vt[(d0 + 4) * 128 + (sr ^ 32)] = v1.x;
    Vt[(d0 + 5) * 128 + (sr ^ 40)] = v1.y;
    Vt[(d0 + 6) * 128 + (sr ^ 48)] = v1.z;
    Vt[(d0 + 7) * 128 + (sr ^ 56)] = v1.w;
  }
}

// Mask tile -> bytes Ml[64][128]; handles bool/int32/float32 source, branch is uniform.
__device__ __forceinline__ void stage_mask(u8t* __restrict__ Ml, const void* __restrict__ maskp,
                                           int fmt, size_t ebase, int mr, int mc)
{
  if (fmt == 1) {
    const u8t* src = (const u8t*)maskp + ebase + mc;
    uint4 a0 = *(const uint4*)src;
    uint4 a1 = *(const uint4*)(src + 16);
    *(uint4*)&Ml[mr * 128 + mc] = a0;
    *(uint4*)&Ml[mr * 128 + mc + 16] = a1;
  } else if (fmt == 0) {
    const int* src = (const int*)maskp + ebase + mc;
    u32t pk[8];
#pragma unroll
    for (int j = 0; j < 8; ++j) {
      int4 vv = *(const int4*)(src + j * 4);
      pk[j] = (vv.x ? 1u : 0u) | ((vv.y ? 1u : 0u) << 8) |
              ((vv.z ? 1u : 0u) << 16) | ((vv.w ? 1u : 0u) << 24);
    }
    uint4 o0; o0.x = pk[0]; o0.y = pk[1]; o0.z = pk[2]; o0.w = pk[3];
    uint4 o1; o1.x = pk[4]; o1.y = pk[5]; o1.z = pk[6]; o1.w = pk[7];
    *(uint4*)&Ml[mr * 128 + mc] = o0;
    *(uint4*)&Ml[mr * 128 + mc + 16] = o1;
  } else {
    const float* src = (const float*)maskp + ebase + mc;
    u32t pk[8];
#pragma unroll
    for (int j = 0; j < 8; ++j) {
      float4 vv = *(const float4*)(src + j * 4);
      pk[j] = (vv.x != 0.f ? 1u : 0u) | ((vv.y != 0.f ? 1u : 0u) << 8) |
              ((vv.z != 0.f ? 1u : 0u) << 16) | ((vv.w != 0.f ? 1u : 0u) << 24);
    }
    uint4 o0; o0.x = pk[0]; o0.y = pk[1]; o0.z = pk[2]; o0.w = pk[3];
    uint4 o1; o1.x = pk[4]; o1.y = pk[5]; o1.z = pk[6]; o1.w = pk[7];
    *(uint4*)&Ml[mr * 128 + mc] = o0;
    *(uint4*)&Ml[mr * 128 + mc + 16] = o1;
  }
}

// ---- fused attention: one block = (b, h, 64 q-rows); 4 waves, 16 q-rows each ----
__global__ __launch_bounds__(256)
void attn_kernel(const u16t* __restrict__ Qb, const u16t* __restrict__ Kb,
                 const u16t* __restrict__ Vb, const void* __restrict__ maskp,
                 const int* __restrict__ flagp,
                 float* __restrict__ ctx, float* __restrict__ probs)
{
  __shared__ u16t Kl[128 * 64];      // K tile [kr][d]
  __shared__ u16t Vt[64 * 128];      // V tile transposed [d][kr]
  __shared__ u8t  Ml[64 * 128];      // mask tile [qr][kr]
  __shared__ u16t Pl[4][16 * 128];   // per-wave P (bf16) [qr16][kr128]

  const int t = threadIdx.x;
  const int w = t >> 6;
  const int l = t & 63;
  const int lq = l & 15, lg = l >> 4;
  const int qt = blockIdx.x, h = blockIdx.y, b = blockIdx.z;
  const int fmt = *flagp;
  const f32x4 fzero = {0.f, 0.f, 0.f, 0.f};

  // Q fragments (A operand, rows w*16+lq), kept in registers for the whole block
  FragU aq[2];
  {
    const u16t* qp = Qb + (size_t)(b * SS + qt * 64 + w * 16 + lq) * DD + h * 64;
    aq[0].h[0] = *(const ushort4*)(qp + 4 * lg);
    aq[0].h[1] = *(const ushort4*)(qp + 4 * lg + 16);
    aq[1].h[0] = *(const ushort4*)(qp + 32 + 4 * lg);
    aq[1].h[1] = *(const ushort4*)(qp + 32 + 4 * lg + 16);
  }

  float m[4], sm[4];
#pragma unroll
  for (int r = 0; r < 4; ++r) { m[r] = -3.0e38f; sm[r] = 0.f; }

  const int sr = t >> 1, sh = t & 1;         // K/V staging coords (row, 32-short half)
  const int mr = t >> 2, mc = (t & 3) * 32;  // mask staging coords
  const size_t mbase0 = (size_t)b * SS * SS + (size_t)(qt * 64 + mr) * SS;

  // ---------------- sweep 1: online row max & exp-sum ----------------
  for (int kt = 0; kt < 16; ++kt) {
    stage_kv(Kb + (size_t)(b * SS + kt * 128 + sr) * DD + h * 64, Kl, sr, sh);
    stage_mask(Ml, maskp, fmt, mbase0 + kt * 128, mr, mc);
    __syncthreads();

    f32x4 sc[8];
#pragma unroll
    for (int nt = 0; nt < 8; ++nt) {
      const int krow = nt * 16 + lq;
      const int xr = (krow & 7) * 8;
      f32x4 a = fzero;
#pragma unroll
      for (int ks = 0; ks < 2; ++ks) {
        FragU bk;
        bk.h[0] = *(const ushort4*)&Kl[krow * 64 + ((ks * 32 + 4 * lg) ^ xr)];
        bk.h[1] = *(const ushort4*)&Kl[krow * 64 + ((ks * 32 + 4 * lg + 16) ^ xr)];
        a = __builtin_amdgcn_mfma_f32_16x16x32_bf16(aq[ks].v, bk.v, a, 0, 0, 0);
      }
#pragma unroll
      for (int r = 0; r < 4; ++r) {
        float s = a[r] * 0.125f;                                 // 1/sqrt(64)
        if (Ml[(w * 16 + 4 * lg + r) * 128 + krow]) s = -1.0e9f; // masked_fill
        sc[nt][r] = s;
      }
    }
#pragma unroll
    for (int r = 0; r < 4; ++r) {
      float tm = sc[0][r];
#pragma unroll
      for (int nt = 1; nt < 8; ++nt) tm = fmaxf(tm, sc[nt][r]);
#pragma unroll
      for (int o = 1; o < 16; o <<= 1) tm = fmaxf(tm, __shfl_xor(tm, o));
      const float nm = fmaxf(m[r], tm);
      float ss = 0.f;
#pragma unroll
      for (int nt = 0; nt < 8; ++nt) ss += __expf(sc[nt][r] - nm);
#pragma unroll
      for (int o = 1; o < 16; o <<= 1) ss += __shfl_xor(ss, o);
      sm[r] = sm[r] * __expf(m[r] - nm) + ss;
      m[r] = nm;
    }
    __syncthreads();
  }

  float inv[4];
#pragma unroll
  for (int r = 0; r < 4; ++r) inv[r] = 1.0f / sm[r];

  f32x4 acco[4];
#pragma unroll
  for (int i = 0; i < 4; ++i) acco[i] = fzero;

  // ---------------- sweep 2: recompute scores -> write probs + PV ----------------
  for (int kt = 0; kt < 16; ++kt) {
    stage_kv(Kb + (size_t)(b * SS + kt * 128 + sr) * DD + h * 64, Kl, sr, sh);
    stage_vt(Vb + (size_t)(b * SS + kt * 128 + sr) * DD + h * 64, Vt, sr, sh);
    stage_mask(Ml, maskp, fmt, mbase0 + kt * 128, mr, mc);
    __syncthreads();

    const size_t prow = ((size_t)(b * HH + h) * SS + qt * 64 + w * 16) * SS + kt * 128;
#pragma unroll
    for (int nt = 0; nt < 8; ++nt) {
      const int krow = nt * 16 + lq;
      const int xr = (krow & 7) * 8;
      f32x4 a = fzero;
#pragma unroll
      for (int ks = 0; ks < 2; ++ks) {
        FragU bk;
        bk.h[0] = *(const ushort4*)&Kl[krow * 64 + ((ks * 32 + 4 * lg) ^ xr)];
        bk.h[1] = *(const ushort4*)&Kl[krow * 64 + ((ks * 32 + 4 * lg + 16) ^ xr)];
        a = __builtin_amdgcn_mfma_f32_16x16x32_bf16(aq[ks].v, bk.v, a, 0, 0, 0);
      }
#pragma unroll
      for (int r = 0; r < 4; ++r) {
        const int qr = 4 * lg + r;
        float s = a[r] * 0.125f;
        if (Ml[(w * 16 + qr) * 128 + krow]) s = -1.0e9f;
        const float p = __expf(s - m[r]) * inv[r];
        probs[prow + (size_t)qr * SS + krow] = p;
        Pl[w][qr * 128 + (krow ^ ((qr & 7) * 8))] = f2bf(p);
      }
    }
    // PV: O += P(16x128) @ V(128x64); A and B use the SAME per-lane k-map (robust)
#pragma unroll
    for (int ks = 0; ks < 4; ++ks) {
      FragU ap;
      const int xp = (lq & 7) * 8;
      ap.h[0] = *(const ushort4*)&Pl[w][lq * 128 + ((ks * 32 + 4 * lg) ^ xp)];
      ap.h[1] = *(const ushort4*)&Pl[w][lq * 128 + ((ks * 32 + 4 * lg + 16) ^ xp)];
#pragma unroll
      for (int n0 = 0; n0 < 4; ++n0) {
        const int d = n0 * 16 + lq;
        const int xv = (d & 7) * 8;
        FragU bv;
        bv.h[0] = *(const ushort4*)&Vt[d * 128 + ((ks * 32 + 4 * lg) ^ xv)];
        bv.h[1] = *(const ushort4*)&Vt[d * 128 + ((ks * 32 + 4 * lg + 16) ^ xv)];
        acco[n0] = __builtin_amdgcn_mfma_f32_16x16x32_bf16(ap.v, bv.v, acco[n0], 0, 0, 0);
      }
    }
    __syncthreads();
  }

  { // ctx epilogue: [B,S,H*DH]
    const size_t crow = (size_t)(b * SS + qt * 64 + w * 16) * DD + h * 64;
#pragma unroll
    for (int n0 = 0; n0 < 4; ++n0)
#pragma unroll
      for (int r = 0; r < 4; ++r)
        ctx[crow + (size_t)(4 * lg + r) * DD + n0 * 16 + lq] = acco[n0][r];
  }
}

extern "C" void kernel_launch(void* const* d_in, const int* in_sizes, int n_in,
                              void* d_out, int out_size, void* d_ws, size_t ws_size,
                              hipStream_t stream)
{
  const float* q   = (const float*)d_in[0];
  const float* k   = (const float*)d_in[1];
  const float* v   = (const float*)d_in[2];
  const void*  msk = d_in[3];
  const float* Wq  = (const float*)d_in[4];
  const float* bq  = (const float*)d_in[5];
  const float* Wk  = (const float*)d_in[6];
  const float* bk  = (const float*)d_in[7];
  const float* Wv  = (const float*)d_in[8];
  const float* bv  = (const float*)d_in[9];
  (void)in_sizes; (void)n_in; (void)out_size; (void)ws_size;

  const size_t NE = (size_t)BB * SS * DD;  // 6,291,456 elements per projected tensor
  u16t* Qb = (u16t*)d_ws;
  u16t* Kb = Qb + NE;
  u16t* Vb = Kb + NE;
  int* flag = (int*)(Vb + NE);

  float* ctx   = (float*)d_out;
  float* probs = ctx + NE;

  detect_kernel<<<1, 256, 0, stream>>>((const u32t*)msk, flag);

  dim3 pg(BB * SS / 64, DD / 128);   // 128 x 6
  proj_kernel<<<pg, 256, 0, stream>>>(q, Wq, bq, Qb);
  proj_kernel<<<pg, 256, 0, stream>>>(k, Wk, bk, Kb);
  proj_kernel<<<pg, 256, 0, stream>>>(v, Wv, bv, Vb);

  attn_kernel<<<dim3(SS / 64, HH, BB), 256, 0, stream>>>(Qb, Kb, Vb, msk, flag, ctx, probs);
}

// Round 2
// 610.552 us; speedup vs baseline: 1.0939x; 1.0939x over previous
//
#include <hip/hip_runtime.h>

// B=4, S=2048, D=768, H=12, DH=64
// out = [ ctx (B*S*D fp32) | probs (B*H*S*S fp32) ]
#define BB 4
#define SS 2048
#define DD 768
#define HH 12

typedef unsigned short u16t;
typedef unsigned char  u8t;
typedef unsigned int   u32t;
typedef __attribute__((ext_vector_type(8))) short bf16x8;
typedef __attribute__((ext_vector_type(4))) float f32x4;

union FragU { bf16x8 v; ushort4 h[2]; };

__device__ __forceinline__ u16t f2bf(float f) {
  union { float fv; u32t u; } x; x.fv = f;
  u32t r = x.u + 0x7FFFu + ((x.u >> 16) & 1u);   // RNE f32 -> bf16
  return (u16t)(r >> 16);
}

// pack 4 bool bytes (0/1) of a u32 into bits 0..3 (bit b = byte b)
__device__ __forceinline__ u32t pack4(u32t w) {
  return ((w & 0x01010101u) * 0x01020408u) >> 24;  // bits 28..31 provably 0
}

// ---- mask dtype detector: flag = 0 int32(0/1), 1 bool bytes, 2 float32(0/1) ----
__global__ void detect_kernel(const u32t* __restrict__ mp, int* __restrict__ flag)
{
  __shared__ int s_isb, s_isf;
  if (threadIdx.x == 0) { s_isb = 0; s_isf = 0; }
  __syncthreads();
  int isb = 0, isf = 0;
  for (int i = threadIdx.x; i < 16384; i += 256) {
    u32t v = mp[i];
    if ((v & 0xFF000000u) == 0x3F000000u) isf = 1;
    else if (v & 0xFFFFFF00u) isb = 1;
  }
  if (isb) atomicOr(&s_isb, 1);
  if (isf) atomicOr(&s_isf, 1);
  __syncthreads();
  if (threadIdx.x == 0) *flag = s_isf ? 2 : (s_isb ? 1 : 0);
}

// ---- projection: out[m][n] = bf16( X[m][:] @ W[:][n] + bias[n] ) ---- (unchanged, passed)
__global__ __launch_bounds__(256)
void proj_kernel(const float* __restrict__ X, const float* __restrict__ W,
                 const float* __restrict__ bias, u16t* __restrict__ out)
{
  __shared__ u16t Al[64 * 40];
  __shared__ u16t Bl[128 * 40];
  const int t = threadIdx.x;
  const int w = t >> 6;
  const int l = t & 63;
  const int lq = l & 15, lg = l >> 4;
  const int m0 = blockIdx.x * 64;
  const int n0 = blockIdx.y * 128;
  const f32x4 fzero = {0.f, 0.f, 0.f, 0.f};

  f32x4 acc[8];
#pragma unroll
  for (int i = 0; i < 8; ++i) acc[i] = fzero;

  const int ar = t >> 2, ac = (t & 3) * 8;
  const int bn = (t & 15) * 8;

  for (int kk = 0; kk < DD; kk += 32) {
    {
      const float* s = X + (size_t)(m0 + ar) * DD + kk + ac;
      float4 f0 = *(const float4*)s;
      float4 f1 = *(const float4*)(s + 4);
      u16t* d = &Al[ar * 40 + ac];
      d[0] = f2bf(f0.x); d[1] = f2bf(f0.y); d[2] = f2bf(f0.z); d[3] = f2bf(f0.w);
      d[4] = f2bf(f1.x); d[5] = f2bf(f1.y); d[6] = f2bf(f1.z); d[7] = f2bf(f1.w);
    }
#pragma unroll
    for (int rep = 0; rep < 2; ++rep) {
      const int c = (t >> 4) + rep * 16;
      const float* s = W + (size_t)(kk + c) * DD + n0 + bn;
      float4 f0 = *(const float4*)s;
      float4 f1 = *(const float4*)(s + 4);
      float fv[8] = {f0.x, f0.y, f0.z, f0.w, f1.x, f1.y, f1.z, f1.w};
#pragma unroll
      for (int e = 0; e < 8; ++e) {
        const int n = bn + e;
        Bl[n * 40 + (c ^ (((n >> 3) & 3) * 8))] = f2bf(fv[e]);
      }
    }
    __syncthreads();
    FragU a;
    const int arow = w * 16 + lq;
    a.h[0] = *(const ushort4*)&Al[arow * 40 + 4 * lg];
    a.h[1] = *(const ushort4*)&Al[arow * 40 + 4 * lg + 16];
#pragma unroll
    for (int nt = 0; nt < 8; ++nt) {
      const int bcol = nt * 16 + lq;
      const int xb = ((bcol >> 3) & 3) * 8;
      FragU bfr;
      bfr.h[0] = *(const ushort4*)&Bl[bcol * 40 + ((4 * lg) ^ xb)];
      bfr.h[1] = *(const ushort4*)&Bl[bcol * 40 + ((4 * lg + 16) ^ xb)];
      acc[nt] = __builtin_amdgcn_mfma_f32_16x16x32_bf16(a.v, bfr.v, acc[nt], 0, 0, 0);
    }
    __syncthreads();
  }
#pragma unroll
  for (int nt = 0; nt < 8; ++nt) {
    const int n = n0 + nt * 16 + lq;
    const float bb = bias[n];
#pragma unroll
    for (int r = 0; r < 4; ++r)
      out[(size_t)(m0 + w * 16 + 4 * lg + r) * DD + n] = f2bf(acc[nt][r] + bb);
  }
}

// V tile transposed: LDS [d 0..63][kr 0..127] bf16: elem(d,kr) at d*128 + (kr ^ ((d&7)*8))
__device__ __forceinline__ void stage_vt(const u16t* __restrict__ src_row,
                                         u16t* __restrict__ Vt, int sr, int sh)
{
#pragma unroll
  for (int i = 0; i < 4; ++i) {
    ushort4 v0 = *(const ushort4*)(src_row + sh * 32 + i * 8);
    ushort4 v1 = *(const ushort4*)(src_row + sh * 32 + i * 8 + 4);
    const int d0 = sh * 32 + i * 8;
    Vt[(d0 + 0) * 128 + (sr ^  0)] = v0.x;
    Vt[(d0 + 1) * 128 + (sr ^  8)] = v0.y;
    Vt[(d0 + 2) * 128 + (sr ^ 16)] = v0.z;
    Vt[(d0 + 3) * 128 + (sr ^ 24)] = v0.w;
    Vt[(d0 + 4) * 128 + (sr ^ 32)] = v1.x;
    Vt[(d0 + 5) * 128 + (sr ^ 40)] = v1.y;
    Vt[(d0 + 6) * 128 + (sr ^ 48)] = v1.z;
    Vt[(d0 + 7) * 128 + (sr ^ 56)] = v1.w;
  }
}

// ---- fused attention, swapped-QK^T structure ----
// one block = (b, h, 64 q-rows); 4 waves, 16 q-rows each.
// Score acc layout (A=K, B=Q): lane (lq,lg) holds S[q=qbase+lq][k=kt*128+nt*16+4lg+r]
// -> P stays in registers and IS the PV A-fragment.
__global__ __launch_bounds__(256, 4)
void attn_kernel(const u16t* __restrict__ Qb, const u16t* __restrict__ Kb,
                 const u16t* __restrict__ Vb, const void* __restrict__ maskp,
                 const int* __restrict__ flagp,
                 float* __restrict__ ctx, float* __restrict__ probs)
{
  __shared__ u16t Kl[128 * 64];   // 16 KB, [kr][d ^ ((kr&7)*8)]
  __shared__ u16t Vt[64 * 128];   // 16 KB, [d][kr ^ ((d&7)*8)]
  __shared__ u32t Mw[64 * 4];     // 1 KB bit-packed mask: word(q,c) bit j = M[q][32c+j]

  const int t = threadIdx.x;
  const int w = t >> 6, l = t & 63;
  const int lq = l & 15, lg = l >> 4;

  // bijective XCD-chunked swizzle: keep the 32 q-blocks of one (b,h) on one XCD
  const int bid = (int)blockIdx.x;                 // 0..1535
  const int lid = (bid & 7) * 192 + (bid >> 3);    // 1536 % 8 == 0 -> bijective
  const int qt = lid & 31;
  const int h  = (lid >> 5) % HH;
  const int b  = lid / (32 * HH);

  const int fmt = *flagp;
  const f32x4 fzero = {0.f, 0.f, 0.f, 0.f};
  const int qbase = qt * 64 + w * 16;

  // Q as B-fragment: col q = qbase+lq, k = d (4lg..+3, +16), per 32-d chunk
  FragU bq_[2];
  {
    const u16t* qp = Qb + (size_t)(b * SS + qbase + lq) * DD + h * 64;
    bq_[0].h[0] = *(const ushort4*)(qp + 4 * lg);
    bq_[0].h[1] = *(const ushort4*)(qp + 4 * lg + 16);
    bq_[1].h[0] = *(const ushort4*)(qp + 32 + 4 * lg);
    bq_[1].h[1] = *(const ushort4*)(qp + 32 + 4 * lg + 16);
  }

  // staging coords
  const int sr = t >> 1, sh = t & 1;   // V staging: row, 32-short half
  const int mq = t >> 2, mc = t & 3;   // mask staging: q-row 0..63, 32-elem chunk 0..3
  const size_t mrow = (size_t)b * SS * SS + (size_t)(qt * 64 + mq) * SS;

  // K stage via global_load_lds w=16: linear LDS dest, inverse-swizzled source
  const int gsr = (l >> 3);            // + (w*4+j)*8
  const int gdd = (l & 7) * 8;

#define STAGE_K(kt_)                                                                   \
  _Pragma("unroll")                                                                    \
  for (int j = 0; j < 4; ++j) {                                                        \
    const int srk = (w * 4 + j) * 8 + gsr;                                             \
    const u16t* gsrc = Kb + (size_t)(b * SS + (kt_) * 128 + srk) * DD + h * 64         \
                          + (gdd ^ ((srk & 7) * 8));                                   \
    __builtin_amdgcn_global_load_lds(                                                  \
        (const __attribute__((address_space(1))) void*)gsrc,                           \
        (__attribute__((address_space(3))) void*)(Kl + (w * 4 + j) * 512), 16, 0, 0);  \
  }

#define STAGE_M(kt_)                                                                   \
  {                                                                                    \
    u32t bits_;                                                                        \
    if (fmt == 1) {                                                                    \
      const u8t* src = (const u8t*)maskp + mrow + (kt_) * 128 + mc * 32;               \
      uint4 a0 = *(const uint4*)src, a1 = *(const uint4*)(src + 16);                   \
      bits_ = pack4(a0.x) | (pack4(a0.y) << 4) | (pack4(a0.z) << 8) |                  \
              (pack4(a0.w) << 12) | (pack4(a1.x) << 16) | (pack4(a1.y) << 20) |        \
              (pack4(a1.z) << 24) | (pack4(a1.w) << 28);                               \
    } else if (fmt == 0) {                                                             \
      const int* src = (const int*)maskp + mrow + (kt_) * 128 + mc * 32;               \
      bits_ = 0;                                                                       \
      _Pragma("unroll")                                                                \
      for (int j2 = 0; j2 < 8; ++j2) {                                                 \
        int4 vv = *(const int4*)(src + j2 * 4);                                        \
        bits_ |= ((vv.x ? 1u : 0u) | ((vv.y ? 1u : 0u) << 1) | ((vv.z ? 1u : 0u) << 2) \
                  | ((vv.w ? 1u : 0u) << 3)) << (j2 * 4);                              \
      }                                                                                \
    } else {                                                                           \
      const float* src = (const float*)maskp + mrow + (kt_) * 128 + mc * 32;           \
      bits_ = 0;                                                                       \
      _Pragma("unroll")                                                                \
      for (int j2 = 0; j2 < 8; ++j2) {                                                 \
        float4 vv = *(const float4*)(src + j2 * 4);                                    \
        bits_ |= ((vv.x != 0.f ? 1u : 0u) | ((vv.y != 0.f ? 1u : 0u) << 1) |           \
                  ((vv.z != 0.f ? 1u : 0u) << 2) | ((vv.w != 0.f ? 1u : 0u) << 3))     \
                 << (j2 * 4);                                                          \
      }                                                                                \
    }                                                                                  \
    Mw[mq * 4 + mc] = bits_;                                                           \
  }

  // scores for one K-tile: S[q=lq][k=nt*16+4lg+r], masked+scaled
#define QKT(sc_)                                                                        \
  {                                                                                     \
    uint4 mv = *(const uint4*)&Mw[(w * 16 + lq) * 4];                                   \
    u32t mwa[4] = {mv.x, mv.y, mv.z, mv.w};                                             \
    _Pragma("unroll")                                                                   \
    for (int nt = 0; nt < 8; ++nt) {                                                    \
      f32x4 a = fzero;                                                                  \
      const int krow = nt * 16 + lq;                                                    \
      const int xr = (krow & 7) * 8;                                                    \
      _Pragma("unroll")                                                                 \
      for (int ks = 0; ks < 2; ++ks) {                                                  \
        FragU ak;                                                                       \
        ak.h[0] = *(const ushort4*)&Kl[krow * 64 + ((ks * 32 + 4 * lg) ^ xr)];          \
        ak.h[1] = *(const ushort4*)&Kl[krow * 64 + ((ks * 32 + 4 * lg + 16) ^ xr)];     \
        a = __builtin_amdgcn_mfma_f32_16x16x32_bf16(ak.v, bq_[ks].v, a, 0, 0, 0);       \
      }                                                                                 \
      const u32t word = mwa[nt >> 1];                                                   \
      const int bb0 = 16 * (nt & 1) + 4 * lg;                                           \
      _Pragma("unroll")                                                                 \
      for (int r = 0; r < 4; ++r) {                                                     \
        float s = a[r] * 0.125f;                                                        \
        if ((word >> (bb0 + r)) & 1) s = -1.0e9f;                                       \
        (sc_)[nt][r] = s;                                                               \
      }                                                                                 \
    }                                                                                   \
  }

  float m = -3.0e38f, sm = 0.f;

  // ---------------- sweep 1: online row max & exp-sum ----------------
  for (int kt = 0; kt < 16; ++kt) {
    STAGE_K(kt)
    STAGE_M(kt)
    __syncthreads();
    f32x4 sc[8];
    QKT(sc)
    float tm = sc[0][0];
#pragma unroll
    for (int nt = 0; nt < 8; ++nt)
#pragma unroll
      for (int r = 0; r < 4; ++r) tm = fmaxf(tm, sc[nt][r]);
    tm = fmaxf(tm, __shfl_xor(tm, 16));
    tm = fmaxf(tm, __shfl_xor(tm, 32));
    const float nm = fmaxf(m, tm);
    float ss = 0.f;
#pragma unroll
    for (int nt = 0; nt < 8; ++nt)
#pragma unroll
      for (int r = 0; r < 4; ++r) ss += __expf(sc[nt][r] - nm);
    ss += __shfl_xor(ss, 16);
    ss += __shfl_xor(ss, 32);
    sm = sm * __expf(m - nm) + ss;
    m = nm;
    __syncthreads();
  }

  const float inv = 1.0f / sm;

  f32x4 acco[4];
#pragma unroll
  for (int i = 0; i < 4; ++i) acco[i] = fzero;

  // ---------------- sweep 2: recompute -> probs (float4) + PV from registers ----------------
  for (int kt = 0; kt < 16; ++kt) {
    STAGE_K(kt)
    stage_vt(Vb + (size_t)(b * SS + kt * 128 + sr) * DD + h * 64, Vt, sr, sh);
    STAGE_M(kt)
    __syncthreads();

    f32x4 sc[8];
    QKT(sc)

    FragU pa[4];
    const size_t prow = ((size_t)(b * HH + h) * SS + qbase + lq) * SS + kt * 128;
#pragma unroll
    for (int nt = 0; nt < 8; ++nt) {
      float4 p;
      p.x = __expf(sc[nt][0] - m) * inv;
      p.y = __expf(sc[nt][1] - m) * inv;
      p.z = __expf(sc[nt][2] - m) * inv;
      p.w = __expf(sc[nt][3] - m) * inv;
      *(float4*)(probs + prow + nt * 16 + 4 * lg) = p;
      ushort4 pb;
      pb.x = f2bf(p.x); pb.y = f2bf(p.y); pb.z = f2bf(p.z); pb.w = f2bf(p.w);
      pa[nt >> 1].h[nt & 1] = pb;
    }
    // PV: O[q][d] += P@V ; A = P (in regs, exact layout), B = V^T from LDS
#pragma unroll
    for (int c = 0; c < 4; ++c) {
#pragma unroll
      for (int n0 = 0; n0 < 4; ++n0) {
        const int d = n0 * 16 + lq;
        const int xv = (d & 7) * 8;
        FragU bv;
        bv.h[0] = *(const ushort4*)&Vt[d * 128 + ((c * 32 + 4 * lg) ^ xv)];
        bv.h[1] = *(const ushort4*)&Vt[d * 128 + ((c * 32 + 4 * lg + 16) ^ xv)];
        acco[n0] = __builtin_amdgcn_mfma_f32_16x16x32_bf16(pa[c].v, bv.v, acco[n0], 0, 0, 0);
      }
    }
    __syncthreads();
  }

  { // ctx epilogue: O[q = qbase + 4lg + r][d = h*64 + n0*16 + lq]
    const size_t crow = (size_t)(b * SS + qbase) * DD + h * 64;
#pragma unroll
    for (int n0 = 0; n0 < 4; ++n0)
#pragma unroll
      for (int r = 0; r < 4; ++r)
        ctx[crow + (size_t)(4 * lg + r) * DD + n0 * 16 + lq] = acco[n0][r];
  }
#undef STAGE_K
#undef STAGE_M
#undef QKT
}

extern "C" void kernel_launch(void* const* d_in, const int* in_sizes, int n_in,
                              void* d_out, int out_size, void* d_ws, size_t ws_size,
                              hipStream_t stream)
{
  const float* q   = (const float*)d_in[0];
  const float* k   = (const float*)d_in[1];
  const float* v   = (const float*)d_in[2];
  const void*  msk = d_in[3];
  const float* Wq  = (const float*)d_in[4];
  const float* bq  = (const float*)d_in[5];
  const float* Wk  = (const float*)d_in[6];
  const float* bk  = (const float*)d_in[7];
  const float* Wv  = (const float*)d_in[8];
  const float* bv  = (const float*)d_in[9];
  (void)in_sizes; (void)n_in; (void)out_size; (void)ws_size;

  const size_t NE = (size_t)BB * SS * DD;
  u16t* Qb = (u16t*)d_ws;
  u16t* Kb = Qb + NE;
  u16t* Vb = Kb + NE;
  int* flag = (int*)(Vb + NE);

  float* ctx   = (float*)d_out;
  float* probs = ctx + NE;

  detect_kernel<<<1, 256, 0, stream>>>((const u32t*)msk, flag);

  dim3 pg(BB * SS / 64, DD / 128);
  proj_kernel<<<pg, 256, 0, stream>>>(q, Wq, bq, Qb);
  proj_kernel<<<pg, 256, 0, stream>>>(k, Wk, bk, Kb);
  proj_kernel<<<pg, 256, 0, stream>>>(v, Wv, bv, Vb);

  attn_kernel<<<dim3(32 * HH * BB), 256, 0, stream>>>(Qb, Kb, Vb, msk, flag, ctx, probs);
}